// Round 9
// baseline (240.133 us; speedup 1.0000x reference)
//
#include <hip/hip_runtime.h>
#include <math.h>

#define BATCH   16384
#define HD      24      // LSTM hidden size
#define NOUTC   24
#define NHID    16
#define NSTEPS  47
#define NG      96
#define GRP     32      // elements per block
#define NTG     12      // thread-groups (j-slot owners) per block
#define JPW     2       // j-slots per thread-group (24/NTG)
#define GPW     8       // gates per thread-group (96/NTG)
#define THREADS 384     // NTG * GRP

__device__ __forceinline__ float fast_sigmoid(float x) {
    float t = __expf(-x);
    return __builtin_amdgcn_rcpf(1.0f + t);
}
__device__ __forceinline__ float fast_tanh(float x) {
    float ax = fabsf(x);
    float t  = __expf(-2.0f * ax);
    float r  = (1.0f - t) * __builtin_amdgcn_rcpf(1.0f + t);
    return copysignf(r, x);
}

__global__ __launch_bounds__(THREADS) void policy_kernel(
    const float* __restrict__ W_ih, const float* __restrict__ W_hh,
    const float* __restrict__ b_ih, const float* __restrict__ b_hh,
    const float* __restrict__ Wl,   const float* __restrict__ bl,
    const float* __restrict__ rnd,  float* __restrict__ out)
{
    __shared__ float sWihB[NG][25];          // [g][c] + bias folded; per-lane act gather (stride 25 -> distinct banks)
    __shared__ float sBias[NG];              // b_ih + b_hh (step 0: a == 0)
    __shared__ float sWhhP[HD][NTG][GPW];    // [k][w][t*2+i] : gate g = t*24 + w*2 + i
    __shared__ float sWlP[HD][NTG][JPW];     // [k][w][i] : n = w*2+i
    __shared__ float sBl[NOUTC];
    __shared__ float hbuf[2][HD][GRP];       // h double-buffered by step parity
    __shared__ float sL[NOUTC][GRP];         // logits exchange
    __shared__ float sPr[GRP][NSTEPS + 2];   // staging for coalesced writes
    __shared__ unsigned char sAct8[GRP][NSTEPS + 2];

    const int tid = threadIdx.x;
    const int w   = tid >> 5;                // thread-group 0..11 (j-slot owner)
    const int e   = tid & 31;                // element within group
    const int b   = blockIdx.x * GRP + e;

    // ---- staging (once per block) ----
    for (int i = tid; i < NG * HD; i += THREADS) {
        int g = i / HD, k = i % HD;
        float bs = b_ih[g] + b_hh[g];
        sWihB[g][k] = W_ih[i] + bs;          // column gather table, bias folded
        int t = g / 24, rem = g % 24, ww = rem / JPW, ii = rem % JPW;
        sWhhP[k][ww][t * JPW + ii] = W_hh[i];
    }
    for (int i = tid; i < NOUTC * HD; i += THREADS) {
        int n = i / HD, k = i % HD;
        sWlP[k][n / JPW][n % JPW] = Wl[i];
    }
    if (tid < NG)    sBias[tid] = b_ih[tid] + b_hh[tid];
    if (tid < NOUTC) sBl[tid]   = bl[tid];
    for (int i = tid; i < HD * GRP; i += THREADS) (&hbuf[0][0][0])[i] = 0.f;  // h0 = 0
    __syncthreads();

    float c_state[JPW];
    #pragma unroll
    for (int i = 0; i < JPW; ++i) c_state[i] = 0.f;
    int act = 0;

    for (int s = 0; s < NSTEPS; ++s) {
        const int par = s & 1;
        const float r = rnd[s * BATCH + b];   // issued early, used in finish

        // ---- gates slice: acc[t*2+i] for gate g = t*24 + w*2 + i ----
        float acc[GPW];
        if (s == 0) {
            #pragma unroll
            for (int t = 0; t < 4; ++t)
                #pragma unroll
                for (int i = 0; i < JPW; ++i)
                    acc[t * JPW + i] = sBias[t * 24 + w * JPW + i];
        } else {
            #pragma unroll
            for (int t = 0; t < 4; ++t)
                #pragma unroll
                for (int i = 0; i < JPW; ++i)
                    acc[t * JPW + i] = sWihB[t * 24 + w * JPW + i][act];
        }
        #pragma unroll 4
        for (int k = 0; k < HD; ++k) {
            float hk = hbuf[par][k][e];                    // 32-wide, broadcast to both half-waves
            const float* wp = &sWhhP[k][w][0];             // 2-addr broadcast per wave (free)
            float4 w0 = *(const float4*)&wp[0];
            float4 w1 = *(const float4*)&wp[4];
            acc[0] = fmaf(hk, w0.x, acc[0]);
            acc[1] = fmaf(hk, w0.y, acc[1]);
            acc[2] = fmaf(hk, w0.z, acc[2]);
            acc[3] = fmaf(hk, w0.w, acc[3]);
            acc[4] = fmaf(hk, w1.x, acc[4]);
            acc[5] = fmaf(hk, w1.y, acc[5]);
            acc[6] = fmaf(hk, w1.z, acc[6]);
            acc[7] = fmaf(hk, w1.w, acc[7]);
        }

        // ---- LSTM cell for own 2 j's; write new h to other parity buffer ----
        #pragma unroll
        for (int i = 0; i < JPW; ++i) {
            float ig = acc[0 * JPW + i], fg = acc[1 * JPW + i];
            float gg = acc[2 * JPW + i], og = acc[3 * JPW + i];
            float si = fast_sigmoid(ig);
            float sf = fast_sigmoid(fg);
            float so = fast_sigmoid(og);
            float tg = fast_tanh(gg);
            float cj = sf * c_state[i] + si * tg;
            c_state[i] = cj;
            hbuf[1 - par][w * JPW + i][e] = so * fast_tanh(cj);
        }
        __syncthreads();   // B: new h visible

        // ---- logits slice: n = w*2+i -> sL ----
        float l0, l1;
        {
            float hk = hbuf[1 - par][0][e];
            const float* wp = &sWlP[0][w][0];
            float2 wv = *(const float2*)&wp[0];
            l0 = hk * wv.x; l1 = hk * wv.y;
        }
        #pragma unroll 4
        for (int k = 1; k < HD; ++k) {
            float hk = hbuf[1 - par][k][e];
            const float* wp = &sWlP[k][w][0];
            float2 wv = *(const float2*)&wp[0];
            l0 = fmaf(hk, wv.x, l0);
            l1 = fmaf(hk, wv.y, l1);
        }
        sL[w * JPW + 0][e] = l0 + sBl[w * JPW + 0];
        sL[w * JPW + 1][e] = l1 + sBl[w * JPW + 1];
        __syncthreads();   // C: logits visible

        // ---- in-register finish (redundant per thread; no more barriers) ----
        const int  cnt = (s + 1) >> 1;
        const bool odd = (s & 1) != 0;
        float v[NOUTC];
        #pragma unroll
        for (int n = 0; n < NOUTC; ++n) v[n] = sL[n][e];
        float m = -INFINITY;
        #pragma unroll
        for (int n = 0; n < NOUTC; ++n) {
            bool msk = odd ? (n < cnt) : (n >= NHID);
            m = fmaxf(m, msk ? v[n] : -INFINITY);
        }
        #pragma unroll
        for (int n = 0; n < NOUTC; ++n) {
            bool msk = odd ? (n < cnt) : (n >= NHID);
            v[n] = msk ? __expf(v[n] - m) : 0.f;    // v[] now holds e[]
        }
        float Z = 0.f;
        #pragma unroll
        for (int n = 0; n < NOUTC; ++n) Z += v[n];  // sequential 0..23, same order as before
        const float rZ = r * Z;                     // cum(e) > r*Z  ==  cum(e/Z) > r  (±1 ulp)
        float cum = 0.f, ea = 0.f;
        int a = 0;
        bool found = false;
        #pragma unroll
        for (int n = 0; n < NOUTC; ++n) {
            cum += v[n];
            if (!found && cum > rZ) { found = true; a = n; ea = v[n]; }
        }
        if (!found) { a = 0; ea = v[0]; }           // unreachable (r<1<=Z), kept for safety
        float pr = ea / Z;                          // IEEE div, mirrors reference p[act]

        if (w == 0) { sPr[e][s] = pr; sAct8[e][s] = (unsigned char)a; }
        act = a;
    }

    __syncthreads();
    // ---- coalesced write-out ----
    const int base = blockIdx.x * GRP * NSTEPS;
    for (int i = tid; i < GRP * NSTEPS; i += THREADS) {
        int rr = i / NSTEPS, ss = i - rr * NSTEPS;
        out[base + i]                          = sPr[rr][ss];
        out[(size_t)BATCH * NSTEPS + base + i] = (float)sAct8[rr][ss];
    }
}

extern "C" void kernel_launch(void* const* d_in, const int* in_sizes, int n_in,
                              void* d_out, int out_size, void* d_ws, size_t ws_size,
                              hipStream_t stream) {
    const float* W_ih = (const float*)d_in[0];
    const float* W_hh = (const float*)d_in[1];
    const float* b_ih = (const float*)d_in[2];
    const float* b_hh = (const float*)d_in[3];
    const float* Wl   = (const float*)d_in[4];
    const float* bl   = (const float*)d_in[5];
    const float* rnd  = (const float*)d_in[6];
    float* o = (float*)d_out;

    policy_kernel<<<BATCH / GRP, THREADS, 0, stream>>>(W_ih, W_hh, b_ih, b_hh, Wl, bl, rnd, o);
}